// Round 2
// baseline (97.272 us; speedup 1.0000x reference)
//
#include <hip/hip_runtime.h>

#define D    32       // feature dim (fixed)
#define BLK  256      // threads per block (4 waves, 64 i-rows per block)
#define NCH  16       // j-chunks per batch -> grid.y

#define LOG2E 1.44269504088896340736f

typedef short  short8  __attribute__((ext_vector_type(8)));
typedef float  floatx4 __attribute__((ext_vector_type(4)));
typedef float  v2f     __attribute__((ext_vector_type(2)));

__device__ __forceinline__ short f2bf(float v) {       // fp32 -> bf16 (RTNE-ish)
    union { float f; unsigned u; } x; x.f = v;
    unsigned r = x.u + 0x7fffu + ((x.u >> 16) & 1u);
    return (short)(r >> 16);
}
__device__ __forceinline__ float bf2f(short h) {
    union { float f; unsigned u; } x;
    x.u = ((unsigned)(unsigned short)h) << 16;
    return x.f;
}
__device__ __forceinline__ float fast_exp2(float x) {
#if __has_builtin(__builtin_amdgcn_exp2f)
    return __builtin_amdgcn_exp2f(x);
#else
    return exp2f(x);
#endif
}

// ---------------------------------------------------------------------------
// Kernel P: per-row precompute + zero-init.
// Layouts (all tile = 16 consecutive j-rows of one batch):
//   f2ab : per tile 1024 shorts: [hi slot0..63][lo slot0..63], slot l=m+16q
//          holding the 8 bf16 of row m, k-octet q  (lane-contiguous MFMA
//          A-fragments readable straight from global, coalesced dwordx4).
//   jpk  : per tile 80 floats: [x[16]][y[16]][z[16]][-w[16]][-fn[16]]
//          (x,y,z = 20*p;  w = log2e*|20p|^2;  fn = log2e*|fea2|^2)
//   xp   : AoS float4 (20px,20py,20pz, log2e*|20p|^2)  -- i-side use
//   f1n  : log2e*|fea1|^2                              -- i-side use
// ---------------------------------------------------------------------------
__global__ __launch_bounds__(BLK) void precompute_kernel(
    const float* __restrict__ points,
    const float* __restrict__ fea1,
    const float* __restrict__ fea2,
    float4* __restrict__ xp,
    float* __restrict__ f1n,
    float* __restrict__ jpk,
    short* __restrict__ f2ab,
    float* __restrict__ acc,
    float* __restrict__ out,
    int BN, int Bsz)
{
    int r = blockIdx.x * BLK + threadIdx.x;
    if (r < Bsz) out[r] = 0.0f;
    if (r >= BN) return;
#pragma unroll
    for (int s = 0; s < 5; ++s) acc[s * BN + r] = 0.0f;

    const float s20 = 20.0f;                 // 1/SIGMA
    float x = points[3*r+0] * s20;
    float y = points[3*r+1] * s20;
    float z = points[3*r+2] * s20;
    float4 v; v.x = x; v.y = y; v.z = z;
    v.w = (x*x + y*y + z*z) * LOG2E;
    xp[r] = v;

    // f1 norm
    const float4* p1 = (const float4*)(fea1 + (size_t)r * D);
    float n1 = 0.f;
#pragma unroll
    for (int k = 0; k < D/4; ++k) {
        float4 a = p1[k];
        n1 = fmaf(a.x,a.x, fmaf(a.y,a.y, fmaf(a.z,a.z, fmaf(a.w,a.w, n1))));
    }
    f1n[r] = n1 * LOG2E;

    // f2: norm + hi/lo split, scattered fragment-major into f2ab
    const int t = r >> 4;                    // global 16-row tile id
    const int m = r & 15;
    const float* p2 = fea2 + (size_t)r * D;
    float n2 = 0.f;
#pragma unroll
    for (int q = 0; q < 4; ++q) {
        float4 v0 = *(const float4*)(p2 + q*8);
        float4 v1 = *(const float4*)(p2 + q*8 + 4);
        float e[8] = {v0.x,v0.y,v0.z,v0.w,v1.x,v1.y,v1.z,v1.w};
        short8 h, l;
#pragma unroll
        for (int k = 0; k < 8; ++k) {
            n2 = fmaf(e[k], e[k], n2);
            short hh = f2bf(e[k]);
            h[k] = hh;
            l[k] = f2bf(e[k] - bf2f(hh));
        }
        size_t off = (size_t)t * 1024 + (size_t)(m + 16*q) * 8;
        *(short8*)&f2ab[off]       = h;   // hi
        *(short8*)&f2ab[off + 512] = l;   // lo
    }

    // j-side scalar pack (negated w and fn so the inner loop is pure add/fma)
    float* jb = jpk + (size_t)t * 80 + m;
    jb[0]  = v.x;
    jb[16] = v.y;
    jb[32] = v.z;
    jb[48] = -v.w;
    jb[64] = -n2 * LOG2E;
}

// ---------------------------------------------------------------------------
// Kernel A: pair loop, LDS-free / barrier-free.
//   Block = 4 independent waves x 16 i-rows; each wave streams its j-chunk's
//   A-fragments and j-scalars straight from global (L1/L2-resident: all 256
//   waves of a (batch,chunk) column read the same 32 KB + 5 KB).
//   A-fragments register-double-buffered one tile ahead; per-pair logit math
//   packed into v_pk_fma_f32 (identical per-pair op order to the previous
//   version -> same per-pair values; only lane accumulation order differs).
// ---------------------------------------------------------------------------
__global__ __launch_bounds__(BLK) void pair_kernel(
    const float* __restrict__ fea1,
    const short* __restrict__ f2ab,
    const float* __restrict__ jpk,
    const float4* __restrict__ xp,
    const float* __restrict__ f1n,
    float* __restrict__ acc,
    int N, int BN)
{
    const int tid  = threadIdx.x;
    const int lane = tid & 63;
    const int wv   = tid >> 6;
    const int m    = lane & 15;        // i-offset (B n-index / C col)
    const int q    = lane >> 4;        // k-octet / j-quad

    const int ibpb  = N / 64;          // i-blocks per batch
    const int b     = blockIdx.x / ibpb;
    const int ibase = blockIdx.x * 64 + wv * 16;
    const int JCH   = N / NCH;
    const int jc0   = blockIdx.y * JCH;
    const int JT    = JCH >> 4;        // j-tiles per wave (16)

    // ---- B fragments: f1 rows of this wave's 16 i's, split hi/lo ----
    const float* f1p = fea1 + (size_t)(ibase + m) * D + q * 8;
    float4 bv0 = *(const float4*)(f1p);
    float4 bv1 = *(const float4*)(f1p + 4);
    float bf[8] = {bv0.x,bv0.y,bv0.z,bv0.w,bv1.x,bv1.y,bv1.z,bv1.w};
    short8 Bhi, Blo;
#pragma unroll
    for (int k = 0; k < 8; ++k) {
        short h = f2bf(bf[k]);
        Bhi[k] = h;
        Blo[k] = f2bf(bf[k] - bf2f(h));
    }

    const float L2 = 2.0f * LOG2E;
    float4 xi = xp[ibase + m];
    float nfi = -f1n[ibase + m];       // -log2e*|f1_i|^2
    v2f vxx = {xi.x * L2, xi.x * L2};
    v2f vxy = {xi.y * L2, xi.y * L2};
    v2f vxz = {xi.z * L2, xi.z * L2};
    v2f vmw = {-xi.w, -xi.w};
    v2f vnf = {nfi, nfi};
    v2f vL2 = {L2, L2};

    v2f sA  = {0.f, 0.f};
    v2f sB  = {0.f, 0.f};
    v2f s2a = {0.f, 0.f};
    v2f s2b = {0.f, 0.f};
    v2f sab = {0.f, 0.f};

    const size_t tg0 = (size_t)(b * N + jc0) >> 4;   // first global j-tile
    const short* pA  = f2ab + tg0 * 1024 + (size_t)lane * 8;
    const float* pJ  = jpk  + tg0 * 80   + (size_t)q * 4;

    short8 Ah = *(const short8*)(pA);
    short8 Al = *(const short8*)(pA + 512);

#define DO_GROUP(c2, x2, y2, z2, w2, f2)                                 \
    do {                                                                 \
        v2f t0 = __builtin_elementwise_fma(x2, vxx, vmw);                \
        t0 = __builtin_elementwise_fma(y2, vxy, t0);                     \
        t0 = __builtin_elementwise_fma(z2, vxz, t0);                     \
        v2f aL = t0 + (w2);                                              \
        v2f bL = __builtin_elementwise_fma(c2, vL2, vnf + (f2));         \
        v2f ea; ea.x = fast_exp2(aL.x); ea.y = fast_exp2(aL.y);          \
        v2f eb; eb.x = fast_exp2(bL.x); eb.y = fast_exp2(bL.y);          \
        sA += ea;                                                        \
        sB += eb;                                                        \
        s2a = __builtin_elementwise_fma(ea, ea, s2a);                    \
        s2b = __builtin_elementwise_fma(eb, eb, s2b);                    \
        sab = __builtin_elementwise_fma(ea, eb, sab);                    \
    } while (0)

    for (int t = 0; t < JT; ++t) {
        // prefetch next tile's A-fragments (clamped on last iter)
        const short* pAn = pA + (t + 1 < JT ? 1024 : 0);
        short8 Ah1 = *(const short8*)(pAn);
        short8 Al1 = *(const short8*)(pAn + 512);

        // j-scalars for this tile: 5 dwordx4 at immediate offsets
        const float* pj = pJ + (size_t)t * 80;
        float4 X = *(const float4*)(pj);
        float4 Y = *(const float4*)(pj + 16);
        float4 Z = *(const float4*)(pj + 32);
        float4 W = *(const float4*)(pj + 48);
        float4 F = *(const float4*)(pj + 64);

        floatx4 c = {0.f, 0.f, 0.f, 0.f};
        c = __builtin_amdgcn_mfma_f32_16x16x32_bf16(Ah, Bhi, c, 0, 0, 0);
        c = __builtin_amdgcn_mfma_f32_16x16x32_bf16(Ah, Blo, c, 0, 0, 0);
        c = __builtin_amdgcn_mfma_f32_16x16x32_bf16(Al, Bhi, c, 0, 0, 0);

        v2f c01; c01.x = c[0]; c01.y = c[1];
        v2f c23; c23.x = c[2]; c23.y = c[3];
        v2f x01; x01.x = X.x; x01.y = X.y;
        v2f x23; x23.x = X.z; x23.y = X.w;
        v2f y01; y01.x = Y.x; y01.y = Y.y;
        v2f y23; y23.x = Y.z; y23.y = Y.w;
        v2f z01; z01.x = Z.x; z01.y = Z.y;
        v2f z23; z23.x = Z.z; z23.y = Z.w;
        v2f w01; w01.x = W.x; w01.y = W.y;
        v2f w23; w23.x = W.z; w23.y = W.w;
        v2f f01; f01.x = F.x; f01.y = F.y;
        v2f f23; f23.x = F.z; f23.y = F.w;

        DO_GROUP(c01, x01, y01, z01, w01, f01);
        DO_GROUP(c23, x23, y23, z23, w23, f23);

        pA = pAn;
        Ah = Ah1; Al = Al1;
    }
#undef DO_GROUP

    // fold the r-parity partial sums
    float vA  = sA.x  + sA.y;
    float vB  = sB.x  + sB.y;
    float v2a = s2a.x + s2a.y;
    float v2b = s2b.x + s2b.y;
    float vab = sab.x + sab.y;

    // ---- reduce the 4 j-quads (lanes sharing lane&15) ----
    vA  += __shfl_xor(vA, 16);  vA  += __shfl_xor(vA, 32);
    vB  += __shfl_xor(vB, 16);  vB  += __shfl_xor(vB, 32);
    v2a += __shfl_xor(v2a, 16); v2a += __shfl_xor(v2a, 32);
    v2b += __shfl_xor(v2b, 16); v2b += __shfl_xor(v2b, 32);
    vab += __shfl_xor(vab, 16); vab += __shfl_xor(vab, 32);

    if (lane < 16) {
        int row = ibase + lane;
        atomicAdd(&acc[0*BN + row], vA);
        atomicAdd(&acc[1*BN + row], v2a);
        atomicAdd(&acc[2*BN + row], vB);
        atomicAdd(&acc[3*BN + row], v2b);
        atomicAdd(&acc[4*BN + row], vab);
    }
}

// ---------------------------------------------------------------------------
// Kernel B: combine per-row sums, weight, reduce into out[b] (out zeroed by P).
//   out[b] = sum_i w_i * ( S2a/A^2 - 2*Sab/(A*B) + S2b/B^2 )
// ---------------------------------------------------------------------------
__global__ __launch_bounds__(BLK) void finalize_kernel(
    const float* __restrict__ acc,
    const float* __restrict__ weights,
    float* __restrict__ out,
    int N, int BN)
{
    int row = blockIdx.x * BLK + threadIdx.x;
    int b   = (blockIdx.x * BLK) / N;

    float A   = acc[0*BN + row];
    float S2a = acc[1*BN + row];
    float Bt  = acc[2*BN + row];
    float S2b = acc[3*BN + row];
    float Sab = acc[4*BN + row];
    float invA = 1.0f / A;
    float invB = 1.0f / Bt;
    float val  = S2a*invA*invA - 2.0f*Sab*invA*invB + S2b*invB*invB;
    float sum  = weights[row] * val;

    __shared__ float red[BLK/64];
    for (int off = 32; off > 0; off >>= 1)
        sum += __shfl_down(sum, off);
    if ((threadIdx.x & 63) == 0) red[threadIdx.x >> 6] = sum;
    __syncthreads();
    if (threadIdx.x == 0) {
        float s = 0.f;
#pragma unroll
        for (int w = 0; w < BLK/64; ++w) s += red[w];
        atomicAdd(&out[b], s);
    }
}

// ---------------------------------------------------------------------------
extern "C" void kernel_launch(void* const* d_in, const int* in_sizes, int n_in,
                              void* d_out, int out_size, void* d_ws, size_t ws_size,
                              hipStream_t stream) {
    const float* points  = (const float*)d_in[0];
    const float* fea1    = (const float*)d_in[1];
    const float* fea2    = (const float*)d_in[2];
    const float* weights = (const float*)d_in[3];
    float* out = (float*)d_out;

    int B  = out_size;          // 2
    int BN = in_sizes[3];       // B*N = 8192
    int N  = BN / B;            // 4096

    // workspace (bytes):
    //   acc  : 5*BN*4          @ 0
    //   xp   : 4*BN*4          @ 5*BN*4
    //   f1n  : BN*4            @ 9*BN*4
    //   jpk  : 5*BN*4          @ 10*BN*4   ((BN/16) tiles * 80 floats)
    //   f2ab : BN*64*2         @ 15*BN*4   ((BN/16) tiles * 1024 shorts)
    float*  acc  = (float*)d_ws;
    float4* xp   = (float4*)((char*)d_ws + (size_t)5  * BN * 4);
    float*  f1n  = (float*)((char*)d_ws + (size_t)9  * BN * 4);
    float*  jpk  = (float*)((char*)d_ws + (size_t)10 * BN * 4);
    short*  f2ab = (short*)((char*)d_ws + (size_t)15 * BN * 4);

    precompute_kernel<<<dim3((BN + BLK - 1) / BLK), dim3(BLK), 0, stream>>>(
        points, fea1, fea2, xp, f1n, jpk, f2ab, acc, out, BN, B);

    dim3 grid(BN / 64, NCH);    // 128 x 16 = 2048 blocks
    pair_kernel<<<grid, dim3(BLK), 0, stream>>>(
        fea1, f2ab, jpk, xp, f1n, acc, N, BN);

    finalize_kernel<<<dim3(BN / BLK), dim3(BLK), 0, stream>>>(acc, weights, out, N, BN);
}

// Round 3
// 88.858 us; speedup vs baseline: 1.0947x; 1.0947x over previous
//
#include <hip/hip_runtime.h>

#define D    32       // feature dim (fixed)
#define BLK  256      // threads per block (4 waves, 64 i-rows per block)
#define NCH  16       // j-chunks per batch -> grid.y
#define SJ   128      // j-rows staged in LDS per stage (8 MFMA tiles)

#define LOG2E 1.44269504088896340736f

typedef short  short8  __attribute__((ext_vector_type(8)));
typedef float  floatx4 __attribute__((ext_vector_type(4)));
typedef float  v2f     __attribute__((ext_vector_type(2)));

__device__ __forceinline__ short f2bf(float v) {       // fp32 -> bf16 (RTNE-ish)
    union { float f; unsigned u; } x; x.f = v;
    unsigned r = x.u + 0x7fffu + ((x.u >> 16) & 1u);
    return (short)(r >> 16);
}
__device__ __forceinline__ float bf2f(short h) {
    union { float f; unsigned u; } x;
    x.u = ((unsigned)(unsigned short)h) << 16;
    return x.f;
}
__device__ __forceinline__ float fast_exp2(float x) {
#if __has_builtin(__builtin_amdgcn_exp2f)
    return __builtin_amdgcn_exp2f(x);
#else
    return exp2f(x);
#endif
}

// ---------------------------------------------------------------------------
// Kernel P: per-row precompute + zero-init + global bf16 hi/lo split of fea2
// stored FRAGMENT-MAJOR (identical to the 84.8us baseline): for row n
// (tile t=n/16, m=n%16), k-octet q, the 8 bf16 go to slot l=m+16q of tile t:
// gX[(t*64 + l)*8 .. +8).
//   xp[r]  = (20*px, 20*py, 20*pz, log2e*|20*p|^2)
//   f1n[r] = log2e*|fea1_r|^2,  f2n[r] = log2e*|fea2_r|^2
// ---------------------------------------------------------------------------
__global__ __launch_bounds__(BLK) void precompute_kernel(
    const float* __restrict__ points,
    const float* __restrict__ fea1,
    const float* __restrict__ fea2,
    float4* __restrict__ xp,
    float* __restrict__ f1n,
    float* __restrict__ f2n,
    short* __restrict__ f2hi,
    short* __restrict__ f2lo,
    float* __restrict__ acc,
    float* __restrict__ out,
    int BN, int Bsz)
{
    int r = blockIdx.x * BLK + threadIdx.x;
    if (r < Bsz) out[r] = 0.0f;
    if (r >= BN) return;
#pragma unroll
    for (int s = 0; s < 5; ++s) acc[s * BN + r] = 0.0f;

    const float s20 = 20.0f;                 // 1/SIGMA
    float x = points[3*r+0] * s20;
    float y = points[3*r+1] * s20;
    float z = points[3*r+2] * s20;
    float4 v; v.x = x; v.y = y; v.z = z;
    v.w = (x*x + y*y + z*z) * LOG2E;
    xp[r] = v;

    // f1 norm
    const float4* p1 = (const float4*)(fea1 + (size_t)r * D);
    float n1 = 0.f;
#pragma unroll
    for (int k = 0; k < D/4; ++k) {
        float4 a = p1[k];
        n1 = fmaf(a.x,a.x, fmaf(a.y,a.y, fmaf(a.z,a.z, fmaf(a.w,a.w, n1))));
    }
    f1n[r] = n1 * LOG2E;

    // f2: norm + hi/lo split, scattered fragment-major
    const int t = r >> 4;                    // global 16-row tile id
    const int m = r & 15;
    const float* p2 = fea2 + (size_t)r * D;
    float n2 = 0.f;
#pragma unroll
    for (int q = 0; q < 4; ++q) {
        float4 v0 = *(const float4*)(p2 + q*8);
        float4 v1 = *(const float4*)(p2 + q*8 + 4);
        float e[8] = {v0.x,v0.y,v0.z,v0.w,v1.x,v1.y,v1.z,v1.w};
        short8 h, l;
#pragma unroll
        for (int k = 0; k < 8; ++k) {
            n2 = fmaf(e[k], e[k], n2);
            short hh = f2bf(e[k]);
            h[k] = hh;
            l[k] = f2bf(e[k] - bf2f(hh));
        }
        size_t off = ((size_t)t * 64 + m + 16*q) * 8;
        *(short8*)&f2hi[off] = h;
        *(short8*)&f2lo[off] = l;
    }
    f2n[r] = n2 * LOG2E;
}

// ---------------------------------------------------------------------------
// Kernel A: pair loop -- baseline LDS-staged structure, MFMA operands SWAPPED.
//   A = f1 (register fragments, built once), B = f2 (LDS fragments per tile).
//   C layout: col = lane&15 = j-within-tile, row = q*4+r = i-within-wave.
//   => each lane's 4 c-values share ONE j: per-tile j-scalar LDS reads drop
//      from 8 (4x sXJ b128 + 4x sFN b32, 16-way redundant broadcast) to 2
//      (1x sXJ b128 + 1x sFN b32); per-i scalars live in 20 registers.
//   LDS-pipe cycles/tile: ~95 -> ~42 (the measured ~20us LDS serialization
//   floor of the 84.8us baseline drops to ~9us; VALU ~13us co-dominant).
//   Spatial logit stays per-pair fp32 VALU (cancellation-sensitive).
// ---------------------------------------------------------------------------
__global__ __launch_bounds__(BLK) void pair_kernel(
    const float* __restrict__ fea1,
    const short* __restrict__ f2hi,
    const short* __restrict__ f2lo,
    const float4* __restrict__ xp,
    const float* __restrict__ f1n,
    const float* __restrict__ f2n,
    float* __restrict__ acc,
    int N, int BN)
{
    __shared__ __align__(16) short sHi[SJ * D];   // 8 KB, fragment-major
    __shared__ __align__(16) short sLo[SJ * D];   // 8 KB
    __shared__ float4 sXJ[SJ];                    // 2 KB
    __shared__ float  sFN[SJ];                    // 512 B

    const int tid  = threadIdx.x;
    const int lane = tid & 63;
    const int wv   = tid >> 6;
    const int m    = lane & 15;        // j-within-tile (C col); f1-frag row
    const int q    = lane >> 4;        // k-octet; i-quad selector

    const int ibpb  = N / 64;          // i-blocks per batch
    const int b     = blockIdx.x / ibpb;
    const int ibase = blockIdx.x * 64 + wv * 16;
    const int JCH   = N / NCH;
    const int jc0   = blockIdx.y * JCH;

    // ---- A fragments: f1 rows of this wave's 16 i's, split hi/lo ----
    // (lane supplies A row m, k-octet q -- same lane mapping as before)
    const float* f1p = fea1 + (size_t)(ibase + m) * D + q * 8;
    float4 bv0 = *(const float4*)(f1p);
    float4 bv1 = *(const float4*)(f1p + 4);
    float bfv[8] = {bv0.x,bv0.y,bv0.z,bv0.w,bv1.x,bv1.y,bv1.z,bv1.w};
    short8 F1hi, F1lo;
#pragma unroll
    for (int k = 0; k < 8; ++k) {
        short h = f2bf(bfv[k]);
        F1hi[k] = h;
        F1lo[k] = f2bf(bfv[k] - bf2f(h));
    }

    // ---- per-i scalars for this lane's 4 output rows (i = ibase+q*4+r) ----
    const float L2 = 2.0f * LOG2E;
    v2f vxx[2], vxy[2], vxz[2], vmw[2], vnf[2];
#pragma unroll
    for (int g = 0; g < 2; ++g) {
        int i0 = ibase + q*4 + g*2;
        float4 a0 = xp[i0];
        float4 a1 = xp[i0 + 1];
        v2f t;
        t.x = a0.x * L2; t.y = a1.x * L2; vxx[g] = t;
        t.x = a0.y * L2; t.y = a1.y * L2; vxy[g] = t;
        t.x = a0.z * L2; t.y = a1.z * L2; vxz[g] = t;
        t.x = -a0.w;     t.y = -a1.w;     vmw[g] = t;
        t.x = -f1n[i0];  t.y = -f1n[i0+1]; vnf[g] = t;
    }
    v2f vL2 = {L2, L2};

    // accumulators: 5 sums x 2 i-pairs (g=0: rows q*4+0,1; g=1: rows q*4+2,3)
    v2f sA2[2]  = {{0.f,0.f},{0.f,0.f}};
    v2f sB2[2]  = {{0.f,0.f},{0.f,0.f}};
    v2f s2a2[2] = {{0.f,0.f},{0.f,0.f}};
    v2f s2b2[2] = {{0.f,0.f},{0.f,0.f}};
    v2f sab2[2] = {{0.f,0.f},{0.f,0.f}};

    const short*  gHi  = f2hi + ((size_t)(b * N + jc0) >> 4) * 512;
    const short*  gLo  = f2lo + ((size_t)(b * N + jc0) >> 4) * 512;
    const float4* xpb  = xp  + (size_t)b * N + jc0;
    const float*  f2nb = f2n + (size_t)b * N + jc0;

    for (int s = 0; s < JCH; s += SJ) {
        // ---- stage: pure contiguous copy (8 KB hi + 8 KB lo) ----
        const uint4* srcH = (const uint4*)(gHi + (size_t)(s >> 4) * 512);
        const uint4* srcL = (const uint4*)(gLo + (size_t)(s >> 4) * 512);
        uint4* dstH = (uint4*)sHi;
        uint4* dstL = (uint4*)sLo;
        dstH[tid]       = srcH[tid];
        dstH[tid + 256] = srcH[tid + 256];
        dstL[tid]       = srcL[tid];
        dstL[tid + 256] = srcL[tid + 256];
        if (tid < SJ) {
            sXJ[tid] = xpb[s + tid];
            sFN[tid] = f2nb[s + tid];
        }
        __syncthreads();

        // ---- compute: 8 16x16 pair tiles ----
#pragma unroll 2
        for (int jt8 = 0; jt8 < SJ/16; ++jt8) {
            const short8 Ahi = *(const short8*)&sHi[(jt8 * 64 + lane) * 8];
            const short8 Alo = *(const short8*)&sLo[(jt8 * 64 + lane) * 8];
            floatx4 c = {0.f, 0.f, 0.f, 0.f};
            // swapped operand order: A=f1 (regs), B=f2 (LDS)
            c = __builtin_amdgcn_mfma_f32_16x16x32_bf16(F1hi, Ahi, c, 0, 0, 0);
            c = __builtin_amdgcn_mfma_f32_16x16x32_bf16(F1hi, Alo, c, 0, 0, 0);
            c = __builtin_amdgcn_mfma_f32_16x16x32_bf16(F1lo, Ahi, c, 0, 0, 0);

            const int jl = jt8 * 16 + m;       // this lane's single j
            float4 xj = sXJ[jl];
            float fnj = sFN[jl];
            v2f xx = {xj.x, xj.x};
            v2f yy = {xj.y, xj.y};
            v2f zz = {xj.z, xj.z};
            v2f ww = {xj.w, xj.w};
            v2f ff = {fnj, fnj};

#pragma unroll
            for (int g = 0; g < 2; ++g) {
                v2f c2; c2.x = c[g*2]; c2.y = c[g*2 + 1];
                v2f t0 = __builtin_elementwise_fma(xx, vxx[g], vmw[g]);
                t0 = __builtin_elementwise_fma(yy, vxy[g], t0);
                t0 = __builtin_elementwise_fma(zz, vxz[g], t0);
                v2f aL = t0 - ww;                                  // log2 spatial
                v2f bL = __builtin_elementwise_fma(c2, vL2, vnf[g] - ff); // log2 feature
                v2f ea; ea.x = fast_exp2(aL.x); ea.y = fast_exp2(aL.y);
                v2f eb; eb.x = fast_exp2(bL.x); eb.y = fast_exp2(bL.y);
                sA2[g]  += ea;
                sB2[g]  += eb;
                s2a2[g] = __builtin_elementwise_fma(ea, ea, s2a2[g]);
                s2b2[g] = __builtin_elementwise_fma(eb, eb, s2b2[g]);
                sab2[g] = __builtin_elementwise_fma(ea, eb, sab2[g]);
            }
        }
        __syncthreads();
    }

    // ---- reduce over m (the 16 lanes of each q-group hold partial sums
    //      over disjoint j subsets for the SAME 4 i-rows) ----
#define RED2(v) do {                                                       \
        v.x += __shfl_xor(v.x, 1); v.x += __shfl_xor(v.x, 2);              \
        v.x += __shfl_xor(v.x, 4); v.x += __shfl_xor(v.x, 8);              \
        v.y += __shfl_xor(v.y, 1); v.y += __shfl_xor(v.y, 2);              \
        v.y += __shfl_xor(v.y, 4); v.y += __shfl_xor(v.y, 8);              \
    } while (0)
#pragma unroll
    for (int g = 0; g < 2; ++g) {
        RED2(sA2[g]); RED2(s2a2[g]); RED2(sB2[g]); RED2(s2b2[g]); RED2(sab2[g]);
    }
#undef RED2

    if (m < 4) {
        int row = ibase + q*4 + m;
        // register-select (no runtime array index -> no scratch)
#define PICK(arr) ((m & 1) ? ((m & 2) ? arr[1].y : arr[0].y)               \
                           : ((m & 2) ? arr[1].x : arr[0].x))
        atomicAdd(&acc[0*BN + row], PICK(sA2));
        atomicAdd(&acc[1*BN + row], PICK(s2a2));
        atomicAdd(&acc[2*BN + row], PICK(sB2));
        atomicAdd(&acc[3*BN + row], PICK(s2b2));
        atomicAdd(&acc[4*BN + row], PICK(sab2));
#undef PICK
    }
}

// ---------------------------------------------------------------------------
// Kernel B: combine per-row sums, weight, reduce into out[b] (out zeroed by P).
//   out[b] = sum_i w_i * ( S2a/A^2 - 2*Sab/(A*B) + S2b/B^2 )
// ---------------------------------------------------------------------------
__global__ __launch_bounds__(BLK) void finalize_kernel(
    const float* __restrict__ acc,
    const float* __restrict__ weights,
    float* __restrict__ out,
    int N, int BN)
{
    int row = blockIdx.x * BLK + threadIdx.x;
    int b   = (blockIdx.x * BLK) / N;

    float A   = acc[0*BN + row];
    float S2a = acc[1*BN + row];
    float Bt  = acc[2*BN + row];
    float S2b = acc[3*BN + row];
    float Sab = acc[4*BN + row];
    float invA = 1.0f / A;
    float invB = 1.0f / Bt;
    float val  = S2a*invA*invA - 2.0f*Sab*invA*invB + S2b*invB*invB;
    float sum  = weights[row] * val;

    __shared__ float red[BLK/64];
    for (int off = 32; off > 0; off >>= 1)
        sum += __shfl_down(sum, off);
    if ((threadIdx.x & 63) == 0) red[threadIdx.x >> 6] = sum;
    __syncthreads();
    if (threadIdx.x == 0) {
        float s = 0.f;
#pragma unroll
        for (int w = 0; w < BLK/64; ++w) s += red[w];
        atomicAdd(&out[b], s);
    }
}

// ---------------------------------------------------------------------------
extern "C" void kernel_launch(void* const* d_in, const int* in_sizes, int n_in,
                              void* d_out, int out_size, void* d_ws, size_t ws_size,
                              hipStream_t stream) {
    const float* points  = (const float*)d_in[0];
    const float* fea1    = (const float*)d_in[1];
    const float* fea2    = (const float*)d_in[2];
    const float* weights = (const float*)d_in[3];
    float* out = (float*)d_out;

    int B  = out_size;          // 2
    int BN = in_sizes[3];       // B*N = 8192
    int N  = BN / B;            // 4096

    // workspace (bytes):
    //   acc  : 5*BN*4   @ 0
    //   xp   : 4*BN*4   @ 5*BN*4
    //   f2n  : BN*4     @ 9*BN*4
    //   f1n  : BN*4     @ 10*BN*4
    //   f2hi : BN*D*2   @ 11*BN*4
    //   f2lo : BN*D*2
    float*  acc  = (float*)d_ws;
    float4* xp   = (float4*)((char*)d_ws + (size_t)5  * BN * 4);
    float*  f2n  = (float*)((char*)d_ws + (size_t)9  * BN * 4);
    float*  f1n  = (float*)((char*)d_ws + (size_t)10 * BN * 4);
    short*  f2hi = (short*)((char*)d_ws + (size_t)11 * BN * 4);
    short*  f2lo = f2hi + (size_t)BN * D;

    precompute_kernel<<<dim3((BN + BLK - 1) / BLK), dim3(BLK), 0, stream>>>(
        points, fea1, fea2, xp, f1n, f2n, f2hi, f2lo, acc, out, BN, B);

    dim3 grid(BN / 64, NCH);    // 128 x 16 = 2048 blocks (8 blocks/CU)
    pair_kernel<<<grid, dim3(BLK), 0, stream>>>(
        fea1, f2hi, f2lo, xp, f1n, f2n, acc, N, BN);

    finalize_kernel<<<dim3(BN / BLK), dim3(BLK), 0, stream>>>(acc, weights, out, N, BN);
}

// Round 4
// 84.411 us; speedup vs baseline: 1.1524x; 1.0527x over previous
//
#include <hip/hip_runtime.h>

#define D    32       // feature dim (fixed)
#define BLK  256      // threads per block (4 waves, 64 i-rows per block)
#define BLKP 64       // precompute block (wide grid: latency-bound kernel)
#define NCH  16       // j-chunks per batch -> grid.y
#define SJ   128      // j-rows staged in LDS per stage (8 MFMA tiles)

#define LOG2E 1.44269504088896340736f

typedef short  short8  __attribute__((ext_vector_type(8)));
typedef float  floatx4 __attribute__((ext_vector_type(4)));
typedef float  v2f     __attribute__((ext_vector_type(2)));

__device__ __forceinline__ short f2bf(float v) {       // fp32 -> bf16 (RTNE-ish)
    union { float f; unsigned u; } x; x.f = v;
    unsigned r = x.u + 0x7fffu + ((x.u >> 16) & 1u);
    return (short)(r >> 16);
}
__device__ __forceinline__ float bf2f(short h) {
    union { float f; unsigned u; } x;
    x.u = ((unsigned)(unsigned short)h) << 16;
    return x.f;
}
__device__ __forceinline__ float fast_exp2(float x) {
#if __has_builtin(__builtin_amdgcn_exp2f)
    return __builtin_amdgcn_exp2f(x);
#else
    return exp2f(x);
#endif
}

// ---------------------------------------------------------------------------
// Kernel P: per-row precompute + zero-init + global bf16 hi/lo split of fea2
// stored FRAGMENT-MAJOR: for row n (tile t=n/16, m=n%16), k-octet q, the
// 8 bf16 go to slot l=m+16q of tile t:  gX[(t*64 + l)*8 .. +8).
// Re-gridded to 128 blocks x 64 threads: same 8192 threads spread over 128
// CUs instead of 32 (kernel is latency-bound, not BW-bound).
// ---------------------------------------------------------------------------
__global__ __launch_bounds__(BLKP) void precompute_kernel(
    const float* __restrict__ points,
    const float* __restrict__ fea1,
    const float* __restrict__ fea2,
    float4* __restrict__ xp,
    float* __restrict__ f1n,
    float* __restrict__ f2n,
    short* __restrict__ f2hi,
    short* __restrict__ f2lo,
    float* __restrict__ acc,
    float* __restrict__ out,
    int BN, int Bsz)
{
    int r = blockIdx.x * BLKP + threadIdx.x;
    if (r < Bsz) out[r] = 0.0f;
    if (r >= BN) return;
#pragma unroll
    for (int s = 0; s < 5; ++s) acc[s * BN + r] = 0.0f;

    const float s20 = 20.0f;                 // 1/SIGMA
    float x = points[3*r+0] * s20;
    float y = points[3*r+1] * s20;
    float z = points[3*r+2] * s20;
    float4 v; v.x = x; v.y = y; v.z = z;
    v.w = (x*x + y*y + z*z) * LOG2E;
    xp[r] = v;

    // f1 norm
    const float4* p1 = (const float4*)(fea1 + (size_t)r * D);
    float n1 = 0.f;
#pragma unroll
    for (int k = 0; k < D/4; ++k) {
        float4 a = p1[k];
        n1 = fmaf(a.x,a.x, fmaf(a.y,a.y, fmaf(a.z,a.z, fmaf(a.w,a.w, n1))));
    }
    f1n[r] = n1 * LOG2E;

    // f2: norm + hi/lo split, scattered fragment-major
    const int t = r >> 4;                    // global 16-row tile id
    const int m = r & 15;
    const float* p2 = fea2 + (size_t)r * D;
    float n2 = 0.f;
#pragma unroll
    for (int q = 0; q < 4; ++q) {
        float4 v0 = *(const float4*)(p2 + q*8);
        float4 v1 = *(const float4*)(p2 + q*8 + 4);
        float e[8] = {v0.x,v0.y,v0.z,v0.w,v1.x,v1.y,v1.z,v1.w};
        short8 h, l;
#pragma unroll
        for (int k = 0; k < 8; ++k) {
            n2 = fmaf(e[k], e[k], n2);
            short hh = f2bf(e[k]);
            h[k] = hh;
            l[k] = f2bf(e[k] - bf2f(hh));
        }
        size_t off = ((size_t)t * 64 + m + 16*q) * 8;
        *(short8*)&f2hi[off] = h;
        *(short8*)&f2lo[off] = l;
    }
    f2n[r] = n2 * LOG2E;
}

// ---------------------------------------------------------------------------
// Kernel A: pair loop (exact 84.8us-baseline structure) with FORCED 8
// waves/SIMD via __launch_bounds__(256, 8) -> VGPR capped at 64.
//   Theory: per-tile dependent chain ~250cyc (LDS ~120 + 3 chained MFMA
//   ~100 + logit/exp ~30) vs ~60 issue-cycles of work; at 4 waves/SIMD
//   coverage is 4*60/250 = 0.96 (borderline stall city); at 8 waves/SIMD
//   coverage is 1.9 -> latency fully hidden. Hot-loop live set is ~50
//   regs (accums 5, B-frags 8, A-frags 8, per-i consts 6, xj 4, addr ~8),
//   so the cap should cost at most cold setup spills.
// ---------------------------------------------------------------------------
__global__ __launch_bounds__(BLK, 8) void pair_kernel(
    const float* __restrict__ fea1,
    const short* __restrict__ f2hi,
    const short* __restrict__ f2lo,
    const float4* __restrict__ xp,
    const float* __restrict__ f1n,
    const float* __restrict__ f2n,
    float* __restrict__ acc,
    int N, int BN)
{
    __shared__ __align__(16) short sHi[SJ * D];   // 8 KB, fragment-major
    __shared__ __align__(16) short sLo[SJ * D];   // 8 KB
    __shared__ float4 sXJ[SJ];                    // 2 KB
    __shared__ float  sFN[SJ];                    // 512 B

    const int tid  = threadIdx.x;
    const int lane = tid & 63;
    const int wv   = tid >> 6;
    const int m    = lane & 15;        // i-offset (B n-index / C col)
    const int q    = lane >> 4;        // k-octet / j-quad

    const int ibpb  = N / 64;          // i-blocks per batch
    const int b     = blockIdx.x / ibpb;
    const int ibase = blockIdx.x * 64 + wv * 16;
    const int JCH   = N / NCH;
    const int jc0   = blockIdx.y * JCH;

    // ---- B fragments: f1 rows of this wave's 16 i's, split hi/lo ----
    const float* f1p = fea1 + (size_t)(ibase + m) * D + q * 8;
    float4 bv0 = *(const float4*)(f1p);
    float4 bv1 = *(const float4*)(f1p + 4);
    float bf[8] = {bv0.x,bv0.y,bv0.z,bv0.w,bv1.x,bv1.y,bv1.z,bv1.w};
    short8 Bhi, Blo;
#pragma unroll
    for (int k = 0; k < 8; ++k) {
        short h = f2bf(bf[k]);
        Bhi[k] = h;
        Blo[k] = f2bf(bf[k] - bf2f(h));
    }

    const float L2 = 2.0f * LOG2E;
    float4 xi = xp[ibase + m];
    float xix = xi.x * L2, xiy = xi.y * L2, xiz = xi.z * L2;
    float mxiw = -xi.w;
    float nfi  = -f1n[ibase + m];      // -log2e*|f1_i|^2

    v2f sAB = {0.f, 0.f};              // (sum e^a, sum e^b)
    v2f s2  = {0.f, 0.f};              // (sum e^2a, sum e^2b)
    float sab = 0.f;                   // sum e^a e^b

    const short*  gHi  = f2hi + ((size_t)(b * N + jc0) >> 4) * 512;
    const short*  gLo  = f2lo + ((size_t)(b * N + jc0) >> 4) * 512;
    const float4* xpb  = xp  + (size_t)b * N + jc0;
    const float*  f2nb = f2n + (size_t)b * N + jc0;

    for (int s = 0; s < JCH; s += SJ) {
        // ---- stage: pure contiguous copy (8 KB hi + 8 KB lo) ----
        const uint4* srcH = (const uint4*)(gHi + (size_t)(s >> 4) * 512);
        const uint4* srcL = (const uint4*)(gLo + (size_t)(s >> 4) * 512);
        uint4* dstH = (uint4*)sHi;
        uint4* dstL = (uint4*)sLo;
        dstH[tid]       = srcH[tid];
        dstH[tid + 256] = srcH[tid + 256];
        dstL[tid]       = srcL[tid];
        dstL[tid + 256] = srcL[tid + 256];
        if (tid < SJ) {
            sXJ[tid] = xpb[s + tid];
            sFN[tid] = f2nb[s + tid];
        }
        __syncthreads();

        // ---- compute: 8 16x16 pair tiles ----
#pragma unroll 2
        for (int jt8 = 0; jt8 < SJ/16; ++jt8) {
            const short8 Ahi = *(const short8*)&sHi[(jt8 * 64 + lane) * 8];
            const short8 Alo = *(const short8*)&sLo[(jt8 * 64 + lane) * 8];
            floatx4 c = {0.f, 0.f, 0.f, 0.f};
            c = __builtin_amdgcn_mfma_f32_16x16x32_bf16(Ahi, Bhi, c, 0, 0, 0);
            c = __builtin_amdgcn_mfma_f32_16x16x32_bf16(Ahi, Blo, c, 0, 0, 0);
            c = __builtin_amdgcn_mfma_f32_16x16x32_bf16(Alo, Bhi, c, 0, 0, 0);
#pragma unroll
            for (int r = 0; r < 4; ++r) {
                int jl = jt8 * 16 + q * 4 + r;
                float4 xj = sXJ[jl];
                float bL = fmaf(c[r], L2, nfi - sFN[jl]);       // log2 feature
                float aL = fmaf(xiz, xj.z,
                             fmaf(xiy, xj.y,
                              fmaf(xix, xj.x, mxiw))) - xj.w;   // log2 spatial
                float ea = fast_exp2(aL);
                float eb = fast_exp2(bL);
                v2f e = {ea, eb};
                sAB += e;                                   // v_pk_add_f32
                s2   = __builtin_elementwise_fma(e, e, s2); // v_pk_fma_f32
                sab  = fmaf(ea, eb, sab);
            }
        }
        __syncthreads();
    }

    // ---- reduce the 4 j-quads (lanes sharing lane&15) ----
    float vA = sAB.x, vB = sAB.y, v2a = s2.x, v2b = s2.y, vab = sab;
    vA  += __shfl_xor(vA, 16);  vA  += __shfl_xor(vA, 32);
    vB  += __shfl_xor(vB, 16);  vB  += __shfl_xor(vB, 32);
    v2a += __shfl_xor(v2a, 16); v2a += __shfl_xor(v2a, 32);
    v2b += __shfl_xor(v2b, 16); v2b += __shfl_xor(v2b, 32);
    vab += __shfl_xor(vab, 16); vab += __shfl_xor(vab, 32);

    if (lane < 16) {
        int row = ibase + lane;
        atomicAdd(&acc[0*BN + row], vA);
        atomicAdd(&acc[1*BN + row], v2a);
        atomicAdd(&acc[2*BN + row], vB);
        atomicAdd(&acc[3*BN + row], v2b);
        atomicAdd(&acc[4*BN + row], vab);
    }
}

// ---------------------------------------------------------------------------
// Kernel B: combine per-row sums, weight, reduce into out[b] (out zeroed by P).
//   out[b] = sum_i w_i * ( S2a/A^2 - 2*Sab/(A*B) + S2b/B^2 )
// ---------------------------------------------------------------------------
__global__ __launch_bounds__(BLK) void finalize_kernel(
    const float* __restrict__ acc,
    const float* __restrict__ weights,
    float* __restrict__ out,
    int N, int BN)
{
    int row = blockIdx.x * BLK + threadIdx.x;
    int b   = (blockIdx.x * BLK) / N;

    float A   = acc[0*BN + row];
    float S2a = acc[1*BN + row];
    float Bt  = acc[2*BN + row];
    float S2b = acc[3*BN + row];
    float Sab = acc[4*BN + row];
    float invA = 1.0f / A;
    float invB = 1.0f / Bt;
    float val  = S2a*invA*invA - 2.0f*Sab*invA*invB + S2b*invB*invB;
    float sum  = weights[row] * val;

    __shared__ float red[BLK/64];
    for (int off = 32; off > 0; off >>= 1)
        sum += __shfl_down(sum, off);
    if ((threadIdx.x & 63) == 0) red[threadIdx.x >> 6] = sum;
    __syncthreads();
    if (threadIdx.x == 0) {
        float s = 0.f;
#pragma unroll
        for (int w = 0; w < BLK/64; ++w) s += red[w];
        atomicAdd(&out[b], s);
    }
}

// ---------------------------------------------------------------------------
extern "C" void kernel_launch(void* const* d_in, const int* in_sizes, int n_in,
                              void* d_out, int out_size, void* d_ws, size_t ws_size,
                              hipStream_t stream) {
    const float* points  = (const float*)d_in[0];
    const float* fea1    = (const float*)d_in[1];
    const float* fea2    = (const float*)d_in[2];
    const float* weights = (const float*)d_in[3];
    float* out = (float*)d_out;

    int B  = out_size;          // 2
    int BN = in_sizes[3];       // B*N = 8192
    int N  = BN / B;            // 4096

    // workspace (bytes):
    //   acc  : 5*BN*4   @ 0
    //   xp   : 4*BN*4   @ 5*BN*4
    //   f2n  : BN*4     @ 9*BN*4
    //   f1n  : BN*4     @ 10*BN*4
    //   f2hi : BN*D*2   @ 11*BN*4
    //   f2lo : BN*D*2
    float*  acc  = (float*)d_ws;
    float4* xp   = (float4*)((char*)d_ws + (size_t)5  * BN * 4);
    float*  f2n  = (float*)((char*)d_ws + (size_t)9  * BN * 4);
    float*  f1n  = (float*)((char*)d_ws + (size_t)10 * BN * 4);
    short*  f2hi = (short*)((char*)d_ws + (size_t)11 * BN * 4);
    short*  f2lo = f2hi + (size_t)BN * D;

    precompute_kernel<<<dim3((BN + BLKP - 1) / BLKP), dim3(BLKP), 0, stream>>>(
        points, fea1, fea2, xp, f1n, f2n, f2hi, f2lo, acc, out, BN, B);

    dim3 grid(BN / 64, NCH);    // 128 x 16 = 2048 blocks (8 blocks/CU)
    pair_kernel<<<grid, dim3(BLK), 0, stream>>>(
        fea1, f2hi, f2lo, xp, f1n, f2n, acc, N, BN);

    finalize_kernel<<<dim3(BN / BLK), dim3(BLK), 0, stream>>>(acc, weights, out, N, BN);
}